// Round 1
// baseline (256.464 us; speedup 1.0000x reference)
//
#include <hip/hip_runtime.h>
#include <hip/hip_bf16.h>
#include <stdint.h>

typedef unsigned short u16;
typedef __attribute__((ext_vector_type(8))) short short8;
typedef __attribute__((ext_vector_type(4))) float f32x4;

#define T_SEQ 2048
#define EMB   1024
#define NH    16
#define HD    64

__device__ __forceinline__ u16 f2bf(float f) {
    union { float f; uint32_t u; } x; x.f = f;
    uint32_t u = x.u;
    uint32_t r = u + 0x7fffu + ((u >> 16) & 1u);   // RNE
    return (u16)(r >> 16);
}

// ---------------- cast fp32 -> bf16 (vectorized) ----------------
__global__ __launch_bounds__(256) void cast_bf16_kernel(const float* __restrict__ in,
                                                        u16* __restrict__ out, int n4) {
    int i = blockIdx.x * 256 + threadIdx.x;
    if (i < n4) {
        float4 v = ((const float4*)in)[i];
        uint32_t p0 = (uint32_t)f2bf(v.x) | ((uint32_t)f2bf(v.y) << 16);
        uint32_t p1 = (uint32_t)f2bf(v.z) | ((uint32_t)f2bf(v.w) << 16);
        ((uint2*)out)[i] = make_uint2(p0, p1);
    }
}

// ---------------- transpose + cast: Wt[n][k] = bf16(W[k][n]) ----------------
__global__ __launch_bounds__(256) void transpose_cast_kernel(const float* __restrict__ W,
                                                             u16* __restrict__ Wt,
                                                             int K, int N) {
    __shared__ float tile[32][33];
    int n0 = blockIdx.x * 32, k0 = blockIdx.y * 32;
    int tx = threadIdx.x, ty = threadIdx.y;   // 32 x 8
#pragma unroll
    for (int i = 0; i < 4; i++)
        tile[ty + i * 8][tx] = W[(k0 + ty + i * 8) * N + n0 + tx];
    __syncthreads();
#pragma unroll
    for (int i = 0; i < 4; i++)
        Wt[(size_t)(n0 + ty + i * 8) * K + k0 + tx] = f2bf(tile[tx][ty + i * 8]);
}

// ---------------- 128x128 tile GEMM core (K=1024, BK=32, 4 waves) ----------------
// A: [M][1024] bf16 row-major, Bt: [N][1024] bf16 row-major (i.e. B transposed)
__device__ __forceinline__ void gemm_tile(const u16* __restrict__ A, const u16* __restrict__ Bt,
                                          int m0, int n0, f32x4 (&acc)[4][4],
                                          u16* As, u16* Bs, int tid) {
    const int lane = tid & 63;
    const int wid  = tid >> 6;
    const int wr = wid >> 1, wc = wid & 1;
    const int g = lane >> 4, r = lane & 15;
#pragma unroll
    for (int m = 0; m < 4; m++)
#pragma unroll
        for (int n = 0; n < 4; n++) acc[m][n] = (f32x4){0.f, 0.f, 0.f, 0.f};

    for (int kk = 0; kk < 1024; kk += 32) {
        __syncthreads();
#pragma unroll
        for (int c = 0; c < 2; c++) {
            int ofs = tid * 16 + c * 4096;       // byte offset into 8KB tile
            int row = ofs >> 6;                  // row stride = 32 bf16 = 64B
            int kb  = (ofs & 63) >> 1;
            *(short8*)&As[ofs >> 1] = *(const short8*)&A[(size_t)(m0 + row) * 1024 + kk + kb];
            *(short8*)&Bs[ofs >> 1] = *(const short8*)&Bt[(size_t)(n0 + row) * 1024 + kk + kb];
        }
        __syncthreads();
        short8 af[4], bf[4];
#pragma unroll
        for (int m = 0; m < 4; m++) af[m] = *(short8*)&As[(wr * 64 + m * 16 + r) * 32 + g * 8];
#pragma unroll
        for (int n = 0; n < 4; n++) bf[n] = *(short8*)&Bs[(wc * 64 + n * 16 + r) * 32 + g * 8];
#pragma unroll
        for (int m = 0; m < 4; m++)
#pragma unroll
            for (int n = 0; n < 4; n++)
                acc[m][n] = __builtin_amdgcn_mfma_f32_16x16x32_bf16(af[m], bf[n], acc[m][n], 0, 0, 0);
    }
}

// ---------------- QKV GEMM: out scattered to Q/K/V [B,H,T,D] bf16 ----------------
__global__ __launch_bounds__(256) void gemm_qkv_kernel(const u16* __restrict__ A, const u16* __restrict__ Bt,
                                                       const float* __restrict__ bias,
                                                       u16* __restrict__ Qo, u16* __restrict__ Ko,
                                                       u16* __restrict__ Vo) {
    __shared__ __align__(16) u16 As[128 * 32];
    __shared__ __align__(16) u16 Bs[128 * 32];
    int tid = threadIdx.x;
    int m0 = blockIdx.x * 128, n0 = blockIdx.y * 128;
    f32x4 acc[4][4];
    gemm_tile(A, Bt, m0, n0, acc, As, Bs, tid);

    int lane = tid & 63, wid = tid >> 6;
    int wr = wid >> 1, wc = wid & 1, g = lane >> 4, r = lane & 15;
#pragma unroll
    for (int m = 0; m < 4; m++) {
#pragma unroll
        for (int n = 0; n < 4; n++) {
            int col = n0 + wc * 64 + n * 16 + r;     // [0,3072)
            float bv = bias[col];
            int which = col >> 10;
            int e = col & 1023;
            int h = e >> 6, d = e & 63;
            u16* dst = (which == 0) ? Qo : ((which == 1) ? Ko : Vo);
#pragma unroll
            for (int j = 0; j < 4; j++) {
                int row = m0 + wr * 64 + m * 16 + g * 4 + j;   // token [0,4096)
                int b = row >> 11, t = row & 2047;
                dst[(((size_t)(b * NH + h)) * T_SEQ + t) * HD + d] = f2bf(acc[m][n][j] + bv);
            }
        }
    }
}

// ---------------- output GEMM: fp32 out = A @ Wout + b ----------------
__global__ __launch_bounds__(256) void gemm_out_kernel(const u16* __restrict__ A, const u16* __restrict__ Bt,
                                                       const float* __restrict__ bias,
                                                       float* __restrict__ out) {
    __shared__ __align__(16) u16 As[128 * 32];
    __shared__ __align__(16) u16 Bs[128 * 32];
    int tid = threadIdx.x;
    int m0 = blockIdx.x * 128, n0 = blockIdx.y * 128;
    f32x4 acc[4][4];
    gemm_tile(A, Bt, m0, n0, acc, As, Bs, tid);

    int lane = tid & 63, wid = tid >> 6;
    int wr = wid >> 1, wc = wid & 1, g = lane >> 4, r = lane & 15;
#pragma unroll
    for (int m = 0; m < 4; m++) {
#pragma unroll
        for (int n = 0; n < 4; n++) {
            int col = n0 + wc * 64 + n * 16 + r;
            float bv = bias[col];
#pragma unroll
            for (int j = 0; j < 4; j++) {
                int row = m0 + wr * 64 + m * 16 + g * 4 + j;
                out[(size_t)row * 1024 + col] = acc[m][n][j] + bv;
            }
        }
    }
}

// ---------------- causal flash attention ----------------
// grid: (T/64, B*H). block: 256 (4 waves, 16 q-rows each). Q,K,V: [B*H][T][64] bf16.
__global__ __launch_bounds__(256) void attn_kernel(const u16* __restrict__ Q, const u16* __restrict__ K,
                                                   const u16* __restrict__ V, u16* __restrict__ O) {
    __shared__ __align__(16) u16 Vt[64][72];        // [d][k], padded: row stride 144B
    __shared__ __align__(16) u16 Ps[4][16][72];     // per-wave P, padded

    const int tid = threadIdx.x;
    const int lane = tid & 63, wid = tid >> 6;
    const int g = lane >> 4, r = lane & 15;
    const int bh = blockIdx.y;
    const int qt = blockIdx.x;
    const int q0 = qt * 64;
    const u16* Qb = Q + (size_t)bh * T_SEQ * HD;
    const u16* Kb = K + (size_t)bh * T_SEQ * HD;
    const u16* Vb = V + (size_t)bh * T_SEQ * HD;

    // Q fragments (A-frag: row = lane%16, 8 contiguous d per lane), hoisted
    short8 qf0 = *(const short8*)&Qb[(size_t)(q0 + wid * 16 + r) * 64 + 8 * g];
    short8 qf1 = *(const short8*)&Qb[(size_t)(q0 + wid * 16 + r) * 64 + 32 + 8 * g];

    float mrun[4], srun[4];
    f32x4 o[4];
#pragma unroll
    for (int j = 0; j < 4; j++) { mrun[j] = -1e30f; srun[j] = 0.f; }
#pragma unroll
    for (int dt = 0; dt < 4; dt++) o[dt] = (f32x4){0.f, 0.f, 0.f, 0.f};

    const int qrow = q0 + wid * 16 + g * 4;   // + j gives this thread's q rows

    for (int kv = 0; kv <= qt; kv++) {
        const int k0 = kv * 64;
        __syncthreads();   // protect Vt from previous iteration's reads
        {   // stage V^T: wave `wid` handles d-rows [wid*16, wid*16+16), lane = k
            const int d0 = wid * 16;
            short8 v0 = *(const short8*)&Vb[(size_t)(k0 + lane) * 64 + d0];
            short8 v1 = *(const short8*)&Vb[(size_t)(k0 + lane) * 64 + d0 + 8];
#pragma unroll
            for (int i = 0; i < 8; i++) Vt[d0 + i][lane] = (u16)v0[i];
#pragma unroll
            for (int i = 0; i < 8; i++) Vt[d0 + 8 + i][lane] = (u16)v1[i];
        }
        __syncthreads();

        // S = Q K^T  (16 q-rows x 64 k-cols per wave)
        f32x4 s[4];
#pragma unroll
        for (int nt = 0; nt < 4; nt++) {
            short8 kf0 = *(const short8*)&Kb[(size_t)(k0 + nt * 16 + r) * 64 + 8 * g];
            short8 kf1 = *(const short8*)&Kb[(size_t)(k0 + nt * 16 + r) * 64 + 32 + 8 * g];
            f32x4 z = (f32x4){0.f, 0.f, 0.f, 0.f};
            z = __builtin_amdgcn_mfma_f32_16x16x32_bf16(qf0, kf0, z, 0, 0, 0);
            z = __builtin_amdgcn_mfma_f32_16x16x32_bf16(qf1, kf1, z, 0, 0, 0);
            s[nt] = z;
        }

        // scale + causal mask + row max
        float rmax[4];
#pragma unroll
        for (int j = 0; j < 4; j++) rmax[j] = -1e30f;
        const bool diag = (kv == qt);
#pragma unroll
        for (int nt = 0; nt < 4; nt++) {
            int kidx = k0 + nt * 16 + r;
#pragma unroll
            for (int j = 0; j < 4; j++) {
                float v = s[nt][j] * 0.125f;
                if (diag && (kidx > qrow + j)) v = -1e30f;
                s[nt][j] = v;
                rmax[j] = fmaxf(rmax[j], v);
            }
        }
#pragma unroll
        for (int msk = 1; msk < 16; msk <<= 1)
#pragma unroll
            for (int j = 0; j < 4; j++)
                rmax[j] = fmaxf(rmax[j], __shfl_xor(rmax[j], msk));

        // online softmax update
        float corr[4], psum[4];
#pragma unroll
        for (int j = 0; j < 4; j++) {
            float mn = fmaxf(mrun[j], rmax[j]);
            corr[j] = __expf(mrun[j] - mn);
            mrun[j] = mn;
            psum[j] = 0.f;
        }
#pragma unroll
        for (int nt = 0; nt < 4; nt++)
#pragma unroll
            for (int j = 0; j < 4; j++) {
                float p = __expf(s[nt][j] - mrun[j]);
                s[nt][j] = p;
                psum[j] += p;
            }
#pragma unroll
        for (int msk = 1; msk < 16; msk <<= 1)
#pragma unroll
            for (int j = 0; j < 4; j++)
                psum[j] += __shfl_xor(psum[j], msk);
#pragma unroll
        for (int j = 0; j < 4; j++) srun[j] = srun[j] * corr[j] + psum[j];
#pragma unroll
        for (int dt = 0; dt < 4; dt++)
#pragma unroll
            for (int j = 0; j < 4; j++) o[dt][j] *= corr[j];

        // P -> LDS (per-wave region; same-wave RW, compiler handles lgkmcnt)
#pragma unroll
        for (int nt = 0; nt < 4; nt++)
#pragma unroll
            for (int j = 0; j < 4; j++)
                Ps[wid][g * 4 + j][nt * 16 + r] = f2bf(s[nt][j]);

        short8 pf0 = *(short8*)&Ps[wid][r][8 * g];
        short8 pf1 = *(short8*)&Ps[wid][r][32 + 8 * g];
#pragma unroll
        for (int dt = 0; dt < 4; dt++) {
            short8 vf0 = *(short8*)&Vt[dt * 16 + r][8 * g];
            short8 vf1 = *(short8*)&Vt[dt * 16 + r][32 + 8 * g];
            o[dt] = __builtin_amdgcn_mfma_f32_16x16x32_bf16(pf0, vf0, o[dt], 0, 0, 0);
            o[dt] = __builtin_amdgcn_mfma_f32_16x16x32_bf16(pf1, vf1, o[dt], 0, 0, 0);
        }
    }

    // epilogue: O -> [B][T][H][D] bf16
    const int b = bh >> 4, h = bh & 15;
#pragma unroll
    for (int j = 0; j < 4; j++) {
        float inv = 1.f / srun[j];
        int q = qrow + j;
#pragma unroll
        for (int dt = 0; dt < 4; dt++) {
            int d = dt * 16 + r;
            O[(((size_t)(b * T_SEQ + q)) * NH + h) * HD + d] = f2bf(o[dt][j] * inv);
        }
    }
}

extern "C" void kernel_launch(void* const* d_in, const int* in_sizes, int n_in,
                              void* d_out, int out_size, void* d_ws, size_t ws_size,
                              hipStream_t stream) {
    const float* x     = (const float*)d_in[0];
    const float* W_qkv = (const float*)d_in[1];
    const float* b_qkv = (const float*)d_in[2];
    const float* W_out = (const float*)d_in[3];
    const float* b_out = (const float*)d_in[4];
    float* out = (float*)d_out;

    char* ws = (char*)d_ws;
    // layout (bytes): xb 8MB | wqkvt 6MB | woutt 2MB | Q 8MB | K 8MB | V 8MB
    // attnb aliases xb (xb dead after gemm_qkv).
    u16* xb    = (u16*)(ws);
    u16* wqkvt = (u16*)(ws + 8388608);
    u16* woutt = (u16*)(ws + 14680064);
    u16* Qp    = (u16*)(ws + 16777216);
    u16* Kp    = (u16*)(ws + 25165824);
    u16* Vp    = (u16*)(ws + 33554432);
    u16* attnb = (u16*)(ws);   // alias xb

    cast_bf16_kernel<<<4096, 256, 0, stream>>>(x, xb, 1048576);
    transpose_cast_kernel<<<dim3(96, 32), dim3(32, 8), 0, stream>>>(W_qkv, wqkvt, 1024, 3072);
    transpose_cast_kernel<<<dim3(32, 32), dim3(32, 8), 0, stream>>>(W_out, woutt, 1024, 1024);
    gemm_qkv_kernel<<<dim3(32, 24), 256, 0, stream>>>(xb, wqkvt, b_qkv, Qp, Kp, Vp);
    attn_kernel<<<dim3(32, 32), 256, 0, stream>>>(Qp, Kp, Vp, attnb);
    gemm_out_kernel<<<dim3(32, 8), 256, 0, stream>>>(attnb, woutt, b_out, out);
}

// Round 2
// 204.773 us; speedup vs baseline: 1.2524x; 1.2524x over previous
//
#include <hip/hip_runtime.h>
#include <hip/hip_bf16.h>
#include <stdint.h>

typedef unsigned short u16;
typedef __attribute__((ext_vector_type(8))) short short8;
typedef __attribute__((ext_vector_type(4))) float f32x4;

#define T_SEQ 2048
#define EMB   1024
#define NH    16
#define HD    64

__device__ __forceinline__ u16 f2bf(float f) {
    union { float f; uint32_t u; } x; x.f = f;
    uint32_t u = x.u;
    uint32_t r = u + 0x7fffu + ((u >> 16) & 1u);   // RNE
    return (u16)(r >> 16);
}

// async global -> LDS, 16 bytes per lane (wave-uniform LDS base + lane*16)
__device__ __forceinline__ void gld16(const void* g, void* l) {
    __builtin_amdgcn_global_load_lds(
        (const __attribute__((address_space(1))) void*)g,
        (__attribute__((address_space(3))) void*)l, 16, 0, 0);
}

// ---------------- cast fp32 -> bf16 (vectorized) ----------------
__global__ __launch_bounds__(256) void cast_bf16_kernel(const float* __restrict__ in,
                                                        u16* __restrict__ out, int n4) {
    int i = blockIdx.x * 256 + threadIdx.x;
    if (i < n4) {
        float4 v = ((const float4*)in)[i];
        uint32_t p0 = (uint32_t)f2bf(v.x) | ((uint32_t)f2bf(v.y) << 16);
        uint32_t p1 = (uint32_t)f2bf(v.z) | ((uint32_t)f2bf(v.w) << 16);
        ((uint2*)out)[i] = make_uint2(p0, p1);
    }
}

// ---------------- transpose + cast: Wt[n][k] = bf16(W[k][n]) ----------------
__global__ __launch_bounds__(256) void transpose_cast_kernel(const float* __restrict__ W,
                                                             u16* __restrict__ Wt,
                                                             int K, int N) {
    __shared__ float tile[32][33];
    int n0 = blockIdx.x * 32, k0 = blockIdx.y * 32;
    int tx = threadIdx.x, ty = threadIdx.y;   // 32 x 8
#pragma unroll
    for (int i = 0; i < 4; i++)
        tile[ty + i * 8][tx] = W[(k0 + ty + i * 8) * N + n0 + tx];
    __syncthreads();
#pragma unroll
    for (int i = 0; i < 4; i++)
        Wt[(size_t)(n0 + ty + i * 8) * K + k0 + tx] = f2bf(tile[tx][ty + i * 8]);
}

// ---------------- 128x128 tile GEMM core (K=1024, BK=32, 4 waves) ----------------
// A: [M][1024] bf16 row-major, Bt: [N][1024] bf16 row-major (i.e. B transposed)
__device__ __forceinline__ void gemm_tile(const u16* __restrict__ A, const u16* __restrict__ Bt,
                                          int m0, int n0, f32x4 (&acc)[4][4],
                                          u16* As, u16* Bs, int tid) {
    const int lane = tid & 63;
    const int wid  = tid >> 6;
    const int wr = wid >> 1, wc = wid & 1;
    const int g = lane >> 4, r = lane & 15;
#pragma unroll
    for (int m = 0; m < 4; m++)
#pragma unroll
        for (int n = 0; n < 4; n++) acc[m][n] = (f32x4){0.f, 0.f, 0.f, 0.f};

    for (int kk = 0; kk < 1024; kk += 32) {
        __syncthreads();
#pragma unroll
        for (int c = 0; c < 2; c++) {
            int ofs = tid * 16 + c * 4096;       // byte offset into 8KB tile
            int row = ofs >> 6;                  // row stride = 32 bf16 = 64B
            int kb  = (ofs & 63) >> 1;
            gld16(&A[(size_t)(m0 + row) * 1024 + kk + kb], &As[ofs >> 1]);
            gld16(&Bt[(size_t)(n0 + row) * 1024 + kk + kb], &Bs[ofs >> 1]);
        }
        __syncthreads();
        short8 af[4], bf[4];
#pragma unroll
        for (int m = 0; m < 4; m++) af[m] = *(short8*)&As[(wr * 64 + m * 16 + r) * 32 + g * 8];
#pragma unroll
        for (int n = 0; n < 4; n++) bf[n] = *(short8*)&Bs[(wc * 64 + n * 16 + r) * 32 + g * 8];
#pragma unroll
        for (int m = 0; m < 4; m++)
#pragma unroll
            for (int n = 0; n < 4; n++)
                acc[m][n] = __builtin_amdgcn_mfma_f32_16x16x32_bf16(af[m], bf[n], acc[m][n], 0, 0, 0);
    }
}

// ---------------- QKV GEMM: Q (pre-scaled by 1/8), K -> [B,H,T,D]; V -> VT [B,H,D,T] ----------------
__global__ __launch_bounds__(256) void gemm_qkv_kernel(const u16* __restrict__ A, const u16* __restrict__ Bt,
                                                       const float* __restrict__ bias,
                                                       u16* __restrict__ Qo, u16* __restrict__ Ko,
                                                       u16* __restrict__ VTo) {
    __shared__ __align__(16) u16 As[128 * 32];
    __shared__ __align__(16) u16 Bs[128 * 32];
    int tid = threadIdx.x;
    int m0 = blockIdx.x * 128, n0 = blockIdx.y * 128;
    f32x4 acc[4][4];
    gemm_tile(A, Bt, m0, n0, acc, As, Bs, tid);

    int lane = tid & 63, wid = tid >> 6;
    int wr = wid >> 1, wc = wid & 1, g = lane >> 4, r = lane & 15;
#pragma unroll
    for (int m = 0; m < 4; m++) {
#pragma unroll
        for (int n = 0; n < 4; n++) {
            int col = n0 + wc * 64 + n * 16 + r;     // [0,3072)
            float bv = bias[col];
            int which = col >> 10;
            int e = col & 1023;
            int h = e >> 6, d = e & 63;
            int row0 = m0 + wr * 64 + m * 16 + g * 4;   // token base, multiple of 4
            int b = row0 >> 11, t0 = row0 & 2047;
            if (which == 2) {
                // V transposed: VT[bh][d][t], 4 consecutive t -> packed 8B store
                ushort4 pk;
                pk.x = f2bf(acc[m][n][0] + bv);
                pk.y = f2bf(acc[m][n][1] + bv);
                pk.z = f2bf(acc[m][n][2] + bv);
                pk.w = f2bf(acc[m][n][3] + bv);
                *(ushort4*)&VTo[(((size_t)(b * NH + h)) * HD + d) * T_SEQ + t0] = pk;
            } else {
                u16* dst = which ? Ko : Qo;
                float sc = which ? 1.0f : 0.125f;     // fold 1/sqrt(D) into Q
#pragma unroll
                for (int j = 0; j < 4; j++)
                    dst[(((size_t)(b * NH + h)) * T_SEQ + t0 + j) * HD + d] = f2bf((acc[m][n][j] + bv) * sc);
            }
        }
    }
}

// ---------------- output GEMM: fp32 out = A @ Wout + b ----------------
__global__ __launch_bounds__(256) void gemm_out_kernel(const u16* __restrict__ A, const u16* __restrict__ Bt,
                                                       const float* __restrict__ bias,
                                                       float* __restrict__ out) {
    __shared__ __align__(16) u16 As[128 * 32];
    __shared__ __align__(16) u16 Bs[128 * 32];
    int tid = threadIdx.x;
    int m0 = blockIdx.x * 128, n0 = blockIdx.y * 128;
    f32x4 acc[4][4];
    gemm_tile(A, Bt, m0, n0, acc, As, Bs, tid);

    int lane = tid & 63, wid = tid >> 6;
    int wr = wid >> 1, wc = wid & 1, g = lane >> 4, r = lane & 15;
#pragma unroll
    for (int m = 0; m < 4; m++) {
#pragma unroll
        for (int n = 0; n < 4; n++) {
            int col = n0 + wc * 64 + n * 16 + r;
            float bv = bias[col];
#pragma unroll
            for (int j = 0; j < 4; j++) {
                int row = m0 + wr * 64 + m * 16 + g * 4 + j;
                out[(size_t)row * 1024 + col] = acc[m][n][j] + bv;
            }
        }
    }
}

// ---------------- causal flash attention (no barriers, balanced pairs) ----------------
// grid: (16, B*H). block: 256 (4 waves x 16 q-rows). Each block does q-tiles
// (x, 31-x) -> exactly 33 KV tiles per block (uniform). Q,K: [B*H][T][64];
// VT: [B*H][64][T]. K prefetched one tile ahead; V loaded at tile top.
__global__ __launch_bounds__(256) void attn_kernel(const u16* __restrict__ Q, const u16* __restrict__ K,
                                                   const u16* __restrict__ VT, u16* __restrict__ O) {
    __shared__ __align__(16) u16 Ps[4][16][72];     // per-wave P transpose buffer

    const int tid = threadIdx.x;
    const int lane = tid & 63, wid = tid >> 6;
    const int g = lane >> 4, r = lane & 15;
    const int bh = blockIdx.y;
    const int b = bh >> 4, h = bh & 15;
    const u16* Qb  = Q  + (size_t)bh * T_SEQ * HD;
    const u16* Kb  = K  + (size_t)bh * T_SEQ * HD;
    const u16* VTb = VT + (size_t)bh * HD * T_SEQ;
    u16 (*myPs)[72] = Ps[wid];

    for (int pass = 0; pass < 2; ++pass) {
        const int qt = pass ? (31 - (int)blockIdx.x) : (int)blockIdx.x;
        const int q0 = qt * 64;
        const int qrow = q0 + wid * 16 + g * 4;     // + j gives this thread's q rows

        // Q fragments (A-frag: row = lane%16, 8 contiguous d per lane)
        short8 qf0 = *(const short8*)&Qb[(size_t)(q0 + wid * 16 + r) * HD + 8 * g];
        short8 qf1 = *(const short8*)&Qb[(size_t)(q0 + wid * 16 + r) * HD + 32 + 8 * g];

        float mrun[4], srun[4];
        f32x4 o[4];
#pragma unroll
        for (int j = 0; j < 4; j++) { mrun[j] = -1e30f; srun[j] = 0.f; }
#pragma unroll
        for (int dt = 0; dt < 4; dt++) o[dt] = (f32x4){0.f, 0.f, 0.f, 0.f};

        // preload K tile 0 fragments (B-frag: col = lane%16, 8 contiguous d)
        short8 kc0[4], kc1[4];
#pragma unroll
        for (int nt = 0; nt < 4; nt++) {
            kc0[nt] = *(const short8*)&Kb[(size_t)(nt * 16 + r) * HD + 8 * g];
            kc1[nt] = *(const short8*)&Kb[(size_t)(nt * 16 + r) * HD + 32 + 8 * g];
        }

        for (int kv = 0; kv <= qt; kv++) {
            const int k0 = kv * 64;

            // V^T fragments for this tile (hidden under QK + softmax)
            short8 vf0[4], vf1[4];
#pragma unroll
            for (int dt = 0; dt < 4; dt++) {
                vf0[dt] = *(const short8*)&VTb[(size_t)(dt * 16 + r) * T_SEQ + k0 + 8 * g];
                vf1[dt] = *(const short8*)&VTb[(size_t)(dt * 16 + r) * T_SEQ + k0 + 32 + 8 * g];
            }

            // S = Q K^T (Q pre-scaled by 1/8)
            f32x4 s[4];
#pragma unroll
            for (int nt = 0; nt < 4; nt++) {
                f32x4 z = (f32x4){0.f, 0.f, 0.f, 0.f};
                z = __builtin_amdgcn_mfma_f32_16x16x32_bf16(qf0, kc0[nt], z, 0, 0, 0);
                z = __builtin_amdgcn_mfma_f32_16x16x32_bf16(qf1, kc1[nt], z, 0, 0, 0);
                s[nt] = z;
            }

            // prefetch next K tile (latency hidden under softmax + PV)
            if (kv < qt) {
                const int k1 = k0 + 64;
#pragma unroll
                for (int nt = 0; nt < 4; nt++) {
                    kc0[nt] = *(const short8*)&Kb[(size_t)(k1 + nt * 16 + r) * HD + 8 * g];
                    kc1[nt] = *(const short8*)&Kb[(size_t)(k1 + nt * 16 + r) * HD + 32 + 8 * g];
                }
            }

            // causal mask (diagonal tile only) + row max
            if (kv == qt) {
#pragma unroll
                for (int nt = 0; nt < 4; nt++) {
                    int kidx = k0 + nt * 16 + r;
#pragma unroll
                    for (int j = 0; j < 4; j++)
                        if (kidx > qrow + j) s[nt][j] = -1e30f;
                }
            }
            float rmax[4];
#pragma unroll
            for (int j = 0; j < 4; j++) rmax[j] = -1e30f;
#pragma unroll
            for (int nt = 0; nt < 4; nt++)
#pragma unroll
                for (int j = 0; j < 4; j++) rmax[j] = fmaxf(rmax[j], s[nt][j]);
#pragma unroll
            for (int msk = 1; msk < 16; msk <<= 1)
#pragma unroll
                for (int j = 0; j < 4; j++)
                    rmax[j] = fmaxf(rmax[j], __shfl_xor(rmax[j], msk));

            // online softmax update
            float corr[4], psum[4];
#pragma unroll
            for (int j = 0; j < 4; j++) {
                float mn = fmaxf(mrun[j], rmax[j]);
                corr[j] = __expf(mrun[j] - mn);
                mrun[j] = mn;
                psum[j] = 0.f;
            }
#pragma unroll
            for (int nt = 0; nt < 4; nt++)
#pragma unroll
                for (int j = 0; j < 4; j++) {
                    float p = __expf(s[nt][j] - mrun[j]);
                    s[nt][j] = p;
                    psum[j] += p;
                }
#pragma unroll
            for (int msk = 1; msk < 16; msk <<= 1)
#pragma unroll
                for (int j = 0; j < 4; j++)
                    psum[j] += __shfl_xor(psum[j], msk);
#pragma unroll
            for (int j = 0; j < 4; j++) srun[j] = srun[j] * corr[j] + psum[j];
#pragma unroll
            for (int dt = 0; dt < 4; dt++)
#pragma unroll
                for (int j = 0; j < 4; j++) o[dt][j] *= corr[j];

            // P transpose via per-wave LDS (same-wave RW, no barrier needed)
#pragma unroll
            for (int nt = 0; nt < 4; nt++)
#pragma unroll
                for (int j = 0; j < 4; j++)
                    myPs[g * 4 + j][nt * 16 + r] = f2bf(s[nt][j]);

            short8 pf0 = *(short8*)&myPs[r][8 * g];
            short8 pf1 = *(short8*)&myPs[r][32 + 8 * g];
#pragma unroll
            for (int dt = 0; dt < 4; dt++) {
                o[dt] = __builtin_amdgcn_mfma_f32_16x16x32_bf16(pf0, vf0[dt], o[dt], 0, 0, 0);
                o[dt] = __builtin_amdgcn_mfma_f32_16x16x32_bf16(pf1, vf1[dt], o[dt], 0, 0, 0);
            }
        }

        // epilogue: O -> [B][T][H][D] bf16
#pragma unroll
        for (int j = 0; j < 4; j++) {
            float inv = 1.f / srun[j];
            int q = qrow + j;
#pragma unroll
            for (int dt = 0; dt < 4; dt++) {
                int d = dt * 16 + r;
                O[(((size_t)(b * T_SEQ + q)) * NH + h) * HD + d] = f2bf(o[dt][j] * inv);
            }
        }
    }
}

extern "C" void kernel_launch(void* const* d_in, const int* in_sizes, int n_in,
                              void* d_out, int out_size, void* d_ws, size_t ws_size,
                              hipStream_t stream) {
    const float* x     = (const float*)d_in[0];
    const float* W_qkv = (const float*)d_in[1];
    const float* b_qkv = (const float*)d_in[2];
    const float* W_out = (const float*)d_in[3];
    const float* b_out = (const float*)d_in[4];
    float* out = (float*)d_out;

    char* ws = (char*)d_ws;
    // layout (bytes): xb 8MB | wqkvt 6MB | woutt 2MB | Q 8MB | K 8MB | VT 8MB
    // attnb aliases xb (xb dead after gemm_qkv).
    u16* xb    = (u16*)(ws);
    u16* wqkvt = (u16*)(ws + 8388608);
    u16* woutt = (u16*)(ws + 14680064);
    u16* Qp    = (u16*)(ws + 16777216);
    u16* Kp    = (u16*)(ws + 25165824);
    u16* VTp   = (u16*)(ws + 33554432);
    u16* attnb = (u16*)(ws);   // alias xb

    cast_bf16_kernel<<<4096, 256, 0, stream>>>(x, xb, 1048576);
    transpose_cast_kernel<<<dim3(96, 32), dim3(32, 8), 0, stream>>>(W_qkv, wqkvt, 1024, 3072);
    transpose_cast_kernel<<<dim3(32, 32), dim3(32, 8), 0, stream>>>(W_out, woutt, 1024, 1024);
    gemm_qkv_kernel<<<dim3(32, 24), 256, 0, stream>>>(xb, wqkvt, b_qkv, Qp, Kp, VTp);
    attn_kernel<<<dim3(16, 32), 256, 0, stream>>>(Qp, Kp, VTp, attnb);
    gemm_out_kernel<<<dim3(32, 8), 256, 0, stream>>>(attnb, woutt, b_out, out);
}